// Round 4
// baseline (552.449 us; speedup 1.0000x reference)
//
#include <hip/hip_runtime.h>

typedef short s8v __attribute__((ext_vector_type(8)));
typedef float f4v __attribute__((ext_vector_type(4)));

static constexpr int Bc = 32, Tq = 256, Tkc = 1024, Dc = 512, Hc = 4;
static constexpr float BN_EPS = 1e-5f;

__device__ inline ushort f2bf(float x) {
    union { float f; unsigned int u; } v; v.f = x;
    unsigned int r = v.u + 0x7fff + ((v.u >> 16) & 1);   // RNE
    return (ushort)(r >> 16);
}

// ---------------------------------------------------------------------------
// Fold eval-mode BN into the following linear layer; weights out in bf16.
// ---------------------------------------------------------------------------
__global__ __launch_bounds__(256) void fold_bn(
    const float* __restrict__ W, const float* __restrict__ gamma,
    const float* __restrict__ beta, const float* __restrict__ mean,
    const float* __restrict__ var, ushort* __restrict__ Wp,
    float* __restrict__ bias, int K)
{
    int n = blockIdx.x;
    int tid = threadIdx.x;
    float acc = 0.f;
    for (int k = tid; k < K; k += 256) {
        float sc = gamma[k] * rsqrtf(var[k] + BN_EPS);
        float sh = beta[k] - mean[k] * sc;
        float w = W[(long)n * K + k];
        Wp[(long)n * K + k] = f2bf(w * sc);
        acc = fmaf(w, sh, acc);
    }
    __shared__ float red[256];
    red[tid] = acc;
    __syncthreads();
    for (int s = 128; s > 0; s >>= 1) {
        if (tid < s) red[tid] += red[tid + s];
        __syncthreads();
    }
    if (tid == 0) bias[n] = red[0];
}

// ---------------------------------------------------------------------------
__global__ __launch_bounds__(256) void f32_to_bf16(
    const float* __restrict__ x, ushort* __restrict__ y)
{
    long i = ((long)blockIdx.x * 256 + threadIdx.x) * 4;
    float4 v = *(const float4*)&x[i];
    ushort4 o = { f2bf(v.x), f2bf(v.y), f2bf(v.z), f2bf(v.w) };
    *(ushort4*)&y[i] = o;
}

// ---------------------------------------------------------------------------
// Fused: h_bf[b][k][d] = bf16(h[b][k][d]) AND hT[b][d][k] = bf16(h[b][k][d])
// ---------------------------------------------------------------------------
__global__ __launch_bounds__(256) void conv_h(
    const float* __restrict__ h, ushort* __restrict__ h_bf,
    ushort* __restrict__ hT)
{
    __shared__ float tl[64][65];
    int b = blockIdx.z, k0 = blockIdx.y * 64, d0 = blockIdx.x * 64;
    int t = threadIdx.x, r = t >> 4, c = (t & 15) * 4;
    const float* hb = h + ((long)b * Tkc + k0) * Dc + d0;
    ushort* sb = h_bf + ((long)b * Tkc + k0) * Dc + d0;
    #pragma unroll
    for (int i = 0; i < 4; i++) {
        int rr = r + i * 16;
        float4 v = *(const float4*)&hb[(long)rr * Dc + c];
        tl[rr][c + 0] = v.x; tl[rr][c + 1] = v.y;
        tl[rr][c + 2] = v.z; tl[rr][c + 3] = v.w;
        ushort4 sv = { f2bf(v.x), f2bf(v.y), f2bf(v.z), f2bf(v.w) };
        *(ushort4*)&sb[(long)rr * Dc + c] = sv;
    }
    __syncthreads();
    ushort* o = hT + ((long)b * Dc + d0) * Tkc + k0;
    #pragma unroll
    for (int i = 0; i < 4; i++) {
        int dr = r + i * 16;
        ushort4 ov = { f2bf(tl[c + 0][dr]), f2bf(tl[c + 1][dr]),
                       f2bf(tl[c + 2][dr]), f2bf(tl[c + 3][dr]) };
        *(ushort4*)&o[(long)dr * Tkc + c] = ov;
    }
}

// ---------------------------------------------------------------------------
// out_c[m][n] = bias[n]  (split-K atomic accumulation target)
// ---------------------------------------------------------------------------
__global__ __launch_bounds__(256) void init_c(
    float* __restrict__ C, const float* __restrict__ bias)
{
    long i = (long)blockIdx.x * 256 + threadIdx.x;   // float4 index
    int n4 = (int)(i & 127);
    float4 b = ((const float4*)bias)[n4];
    ((float4*)C)[i] = b;
}

// ---------------------------------------------------------------------------
// bf16 MFMA GEMM (NT): C[m,n] = sum_k A[m,k]*B[n,k] (+bias[n])
// 128x128 tile, BK=64 (32 MFMA per barrier window), 4 waves in 2x2.
// (proven round-0 kernel, 4 blocks/CU)
// ---------------------------------------------------------------------------
typedef __attribute__((address_space(1))) void gvoid;
typedef __attribute__((address_space(3))) void lvoid;

#define GLOAD(gp, lp) __builtin_amdgcn_global_load_lds((gvoid*)(gp), (lvoid*)(lp), 16, 0, 0)
#define BAR() asm volatile("s_barrier" ::: "memory")
#define WAITV0() asm volatile("s_waitcnt vmcnt(0)" ::: "memory")

__global__ __launch_bounds__(256, 4) void gemm_mfma(
    const ushort* __restrict__ A, const ushort* __restrict__ B,
    float* __restrict__ Cf, ushort* __restrict__ Cb,
    const float* __restrict__ bias, int atom,
    int K, int lda, int ldb, int ldc,
    long sAh, long sAb, long sBh, long sBb, long sCh, long sCb,
    int nB, int nxs, int zbits)
{
    int bx = blockIdx.x;
    int z = bx & ((1 << zbits) - 1);
    int j2 = bx >> zbits;
    int gx = j2 & ((1 << nxs) - 1);
    int gy = j2 >> nxs;

    int hh = z / nB, bb = z - hh * nB;
    A += hh * sAh + bb * sAb;
    B += hh * sBh + bb * sBb;
    long coff = hh * sCh + bb * sCb;

    __shared__ ushort Als[128 * 64];
    __shared__ ushort Bls[128 * 64];

    int tid = threadIdx.x;
    int l = tid & 63, w = tid >> 6;
    int m0 = gy * 128, n0 = gx * 128;

    const ushort* gA[4]; const ushort* gB[4];
    ushort* lA[4]; ushort* lB[4];
    #pragma unroll
    for (int j = 0; j < 4; j++) {
        int L = (w * 4 + j) * 64 + l;
        int m = L >> 3, c = L & 7;
        int kof = (c ^ ((m >> 1) & 7)) * 8;
        gA[j] = A + (long)(m0 + m) * lda + kof;
        gB[j] = B + (long)(n0 + m) * ldb + kof;
        lA[j] = &Als[(w * 4 + j) * 512];
        lB[j] = &Bls[(w * 4 + j) * 512];
    }

    int wm = (w >> 1) * 64, wn = (w & 1) * 64;
    int fr = l & 15, kc = l >> 4;

    int aidx[2][4], bidx[2][4];
    #pragma unroll
    for (int kk = 0; kk < 2; kk++)
        #pragma unroll
        for (int t = 0; t < 4; t++) {
            int ra = wm + t * 16 + fr;
            aidx[kk][t] = (ra * 8 + ((kk * 4 + kc) ^ ((ra >> 1) & 7))) * 8;
            int rb = wn + t * 16 + fr;
            bidx[kk][t] = (rb * 8 + ((kk * 4 + kc) ^ ((rb >> 1) & 7))) * 8;
        }

    f4v acc[4][4] = {};

    for (int k0 = 0; k0 < K; k0 += 64) {
        #pragma unroll
        for (int j = 0; j < 4; j++) {
            GLOAD(gA[j] + k0, lA[j]);
            GLOAD(gB[j] + k0, lB[j]);
        }
        __syncthreads();
        #pragma unroll
        for (int kk = 0; kk < 2; kk++) {
            s8v af[4], bfv[4];
            #pragma unroll
            for (int t = 0; t < 4; t++) af[t]  = *(const s8v*)&Als[aidx[kk][t]];
            #pragma unroll
            for (int t = 0; t < 4; t++) bfv[t] = *(const s8v*)&Bls[bidx[kk][t]];
            #pragma unroll
            for (int i = 0; i < 4; i++)
                #pragma unroll
                for (int jj = 0; jj < 4; jj++)
                    acc[i][jj] = __builtin_amdgcn_mfma_f32_16x16x32_bf16(
                        af[i], bfv[jj], acc[i][jj], 0, 0, 0);
        }
        __syncthreads();
    }

    #pragma unroll
    for (int i = 0; i < 4; i++) {
        #pragma unroll
        for (int jj = 0; jj < 4; jj++) {
            int n = n0 + wn + jj * 16 + fr;
            float bv = bias ? bias[n] : 0.f;
            #pragma unroll
            for (int r = 0; r < 4; r++) {
                int m = m0 + wm + i * 16 + kc * 4 + r;
                float v = acc[i][jj][r] + bv;
                long off = coff + (long)m * ldc + n;
                if (atom)    atomicAdd(&Cf[off], v);
                else if (Cb) Cb[off] = f2bf(v);
                else         Cf[off] = v;
            }
        }
    }
}

// ---------------------------------------------------------------------------
// Fused scores + softmax: block tile 64 rows x 1024 cols (full softmax axis),
// K=512.  8 waves, each 64x128 (4 m-frags x 8 n-frags, acc 128 VGPR).
// LDS: fragment-linear layout — each 16x32 operand sub-block stored as 1 KB
// with slot = lane (filled via per-lane permuted global_load_lds source),
// so ds_read_b128 is lane-linear and conflict-free.  BK=32, double-buffered
// (2 x 68 KB), stage(t+1) overlaps compute(t).
// Epilogue: in-register row max/sum (shfl over 16-lane group + LDS over
// 8 waves), write normalized f32 out_a and bf16 a_bf once.
// e accumulation order identical to the old e-GEMM (sequential k) ->
// out_a values unchanged.
// ---------------------------------------------------------------------------
#define FBUF 34816   // ushort offset of buffer 1 (69632 B per buffer)

#define FSTG(t, bufb) do { \
    if (w < 4) GLOAD(gAs + (t) * 32, &lds[(bufb) + w * 512]); \
    _Pragma("unroll") \
    for (int j = 0; j < 8; j++) \
        GLOAD(gBs + j * 8192 + (t) * 32, &lds[(bufb) + 2048 + (w * 8 + j) * 512]); \
} while (0)

#define FCOMP(bufb) do { \
    s8v aF[4]; \
    _Pragma("unroll") \
    for (int mi = 0; mi < 4; mi++) \
        aF[mi] = *(const s8v*)&lds[(bufb) + mi * 512 + l * 8]; \
    _Pragma("unroll") \
    for (int j = 0; j < 8; j++) { \
        s8v bF = *(const s8v*)&lds[(bufb) + 2048 + (w * 8 + j) * 512 + l * 8]; \
        _Pragma("unroll") \
        for (int mi = 0; mi < 4; mi++) \
            acc[mi][j] = __builtin_amdgcn_mfma_f32_16x16x32_bf16( \
                aF[mi], bF, acc[mi][j], 0, 0, 0); \
    } \
} while (0)

__global__ __launch_bounds__(512, 2) void fused_esm(
    const ushort* __restrict__ ms, const ushort* __restrict__ mh,
    float* __restrict__ outA, ushort* __restrict__ aB, int lognb)
{
    __shared__ ushort lds[69632];   // 136 KiB: 2 x (A 4KB + B 64KB)

    int bx = blockIdx.x;
    int bbl = bx & ((1 << lognb) - 1);       // batch (local) — XCD co-located
    int hm = bx >> lognb;
    int hh = hm >> 2, mt = hm & 3;           // head, m-tile (64 rows)
    int nb = 1 << lognb;

    int tid = threadIdx.x;
    int w = tid >> 6, l = tid & 63;

    // staging sources (per-lane permuted so LDS dest base+lane*16 yields the
    // fragment-linear layout): slot l <- [row l&15][k-chunk l>>4]
    const ushort* gAs = ms + ((long)(bbl * 256 + mt * 64 + (w & 3) * 16 + (l & 15))) * 2048
                           + hh * 512 + ((l >> 4) * 8);
    const ushort* gBs = mh + ((long)(bbl * 1024 + w * 128 + (l & 15))) * 512
                           + ((l >> 4) * 8);

    f4v acc[4][8] = {};

    FSTG(0, 0); WAITV0(); BAR();
    #pragma unroll 1
    for (int t2 = 0; t2 < 7; ++t2) {
        FSTG(2 * t2 + 1, FBUF); FCOMP(0);    WAITV0(); BAR();
        FSTG(2 * t2 + 2, 0);    FCOMP(FBUF); WAITV0(); BAR();
    }
    FSTG(15, FBUF); FCOMP(0); WAITV0(); BAR();
    FCOMP(FBUF);

    // ---------------- softmax epilogue ----------------
    __syncthreads();
    float* red = (float*)lds;       // [8][64] partials + [64] finals @512
    int g4 = l >> 4;

    float mxv[4][4];
    #pragma unroll
    for (int mi = 0; mi < 4; mi++)
        #pragma unroll
        for (int r = 0; r < 4; r++) {
            float m_ = acc[mi][0][r];
            #pragma unroll
            for (int j = 1; j < 8; j++) m_ = fmaxf(m_, acc[mi][j][r]);
            m_ = fmaxf(m_, __shfl_xor(m_, 1, 64));
            m_ = fmaxf(m_, __shfl_xor(m_, 2, 64));
            m_ = fmaxf(m_, __shfl_xor(m_, 4, 64));
            m_ = fmaxf(m_, __shfl_xor(m_, 8, 64));
            mxv[mi][r] = m_;
        }
    if ((l & 15) == 0) {
        #pragma unroll
        for (int mi = 0; mi < 4; mi++)
            #pragma unroll
            for (int r = 0; r < 4; r++)
                red[w * 64 + mi * 16 + g4 * 4 + r] = mxv[mi][r];
    }
    __syncthreads();
    if (tid < 64) {
        float m_ = red[tid];
        #pragma unroll
        for (int ww = 1; ww < 8; ww++) m_ = fmaxf(m_, red[ww * 64 + tid]);
        red[512 + tid] = m_;
    }
    __syncthreads();
    #pragma unroll
    for (int mi = 0; mi < 4; mi++) {
        float4 f = *(const float4*)&red[512 + mi * 16 + g4 * 4];
        mxv[mi][0] = f.x; mxv[mi][1] = f.y; mxv[mi][2] = f.z; mxv[mi][3] = f.w;
    }

    float smv[4][4];
    #pragma unroll
    for (int mi = 0; mi < 4; mi++)
        #pragma unroll
        for (int r = 0; r < 4; r++) {
            float s_ = 0.f;
            #pragma unroll
            for (int j = 0; j < 8; j++) {
                float e = __expf(acc[mi][j][r] - mxv[mi][r]);
                acc[mi][j][r] = e;
                s_ += e;
            }
            s_ += __shfl_xor(s_, 1, 64);
            s_ += __shfl_xor(s_, 2, 64);
            s_ += __shfl_xor(s_, 4, 64);
            s_ += __shfl_xor(s_, 8, 64);
            smv[mi][r] = s_;
        }
    if ((l & 15) == 0) {
        #pragma unroll
        for (int mi = 0; mi < 4; mi++)
            #pragma unroll
            for (int r = 0; r < 4; r++)
                red[w * 64 + mi * 16 + g4 * 4 + r] = smv[mi][r];
    }
    __syncthreads();
    if (tid < 64) {
        float s_ = red[tid];
        #pragma unroll
        for (int ww = 1; ww < 8; ww++) s_ += red[ww * 64 + tid];
        red[512 + tid] = 1.f / s_;
    }
    __syncthreads();
    #pragma unroll
    for (int mi = 0; mi < 4; mi++) {
        float4 f = *(const float4*)&red[512 + mi * 16 + g4 * 4];
        smv[mi][0] = f.x; smv[mi][1] = f.y; smv[mi][2] = f.z; smv[mi][3] = f.w;
    }

    float* oA = outA + ((long)(hh * 32 + bbl) * 256 + mt * 64) * 1024;
    ushort* oB = aB + ((long)(hh * nb + bbl) * 256 + mt * 64) * 1024;
    #pragma unroll
    for (int mi = 0; mi < 4; mi++)
        #pragma unroll
        for (int j = 0; j < 8; j++)
            #pragma unroll
            for (int r = 0; r < 4; r++) {
                int rr = mi * 16 + g4 * 4 + r;
                int cc = w * 128 + j * 16 + (l & 15);
                float p = acc[mi][j][r] * smv[mi][r];
                oA[(long)rr * 1024 + cc] = p;
                oB[(long)rr * 1024 + cc] = f2bf(p);
            }
}

// ---------------------------------------------------------------------------
extern "C" void kernel_launch(void* const* d_in, const int* in_sizes, int n_in,
                              void* d_out, int out_size, void* d_ws, size_t ws_size,
                              hipStream_t stream)
{
    const float* s     = (const float*)d_in[0];
    const float* h     = (const float*)d_in[1];
    const float* phi_g = (const float*)d_in[2];
    const float* phi_b = (const float*)d_in[3];
    const float* phi_m = (const float*)d_in[4];
    const float* phi_v = (const float*)d_in[5];
    const float* W_phi = (const float*)d_in[6];
    const float* psi_g = (const float*)d_in[7];
    const float* psi_b = (const float*)d_in[8];
    const float* psi_m = (const float*)d_in[9];
    const float* psi_v = (const float*)d_in[10];
    const float* W_psi = (const float*)d_in[11];
    const float* red_g = (const float*)d_in[12];
    const float* red_b = (const float*)d_in[13];
    const float* red_m = (const float*)d_in[14];
    const float* red_v = (const float*)d_in[15];
    const float* W_red = (const float*)d_in[16];

    float* out_a = (float*)d_out;                         // (H,B,Tq,Tk) f32
    float* out_c = out_a + (long)Hc * Bc * Tq * Tkc;      // (B,Tq,D)  f32

    char* p = (char*)d_ws;
    ushort* Wphi_b = (ushort*)p;  p += (long)2048 * 512 * 2;
    ushort* Wpsi_b = (ushort*)p;  p += (long)512 * 512 * 2;
    ushort* Wred_b = (ushort*)p;  p += (long)512 * 2048 * 2;
    float* bias_phi = (float*)p;  p += 2048 * 4;
    float* bias_psi = (float*)p;  p += 512 * 4;
    float* bias_red = (float*)p;  p += 512 * 4;
    ushort* s_bf  = (ushort*)p;   p += (long)8192 * 512 * 2;
    ushort* h_bf  = (ushort*)p;   p += (long)32768 * 512 * 2;
    ushort* hT_bf = (ushort*)p;   p += (long)32768 * 512 * 2;
    ushort* ms_bf = (ushort*)p;   p += (long)8192 * 2048 * 2;
    ushort* mh_bf = (ushort*)p;   p += (long)32768 * 512 * 2;

    // a_bf / ctx homes: s_bf+h_bf is a dead 40 MB region once ms/mh exist.
    // Choose batch-split S so a_bf (64/S MB) + ctx (32/S MB) fit without
    // assuming workspace size.
    long avail = (long)ws_size - (p - (char*)d_ws);
    int S, lognb;
    ushort *aReg, *ctxReg;
    if (avail >= (long)64 * 1024 * 1024) {
        S = 1; lognb = 5;
        aReg = (ushort*)p;                     // 64 MB tail
        ctxReg = s_bf;                         // 32 MB in dead s+h region
    } else if (avail >= (long)16 * 1024 * 1024) {
        S = 2; lognb = 4;
        aReg = s_bf;                           // 32 MB in dead s+h region
        ctxReg = (ushort*)p;                   // 16 MB tail
    } else {
        S = 4; lognb = 3;
        aReg = s_bf;                           // 16 MB
        ctxReg = s_bf + (long)8 * 1024 * 1024; // 8 MB at +16 MB (dead h_bf)
    }
    int nb = 32 / S;

    // 1) BN folds
    fold_bn<<<2048, 256, 0, stream>>>(W_phi, phi_g, phi_b, phi_m, phi_v, Wphi_b, bias_phi, 512);
    fold_bn<<<512,  256, 0, stream>>>(W_psi, psi_g, psi_b, psi_m, psi_v, Wpsi_b, bias_psi, 512);
    fold_bn<<<512,  256, 0, stream>>>(W_red, red_g, red_b, red_m, red_v, Wred_b, bias_red, 2048);

    // 2) activation converts (+ c-output bias init for split-K atomics)
    f32_to_bf16<<<4096, 256, 0, stream>>>(s, s_bf);
    conv_h<<<dim3(8, 16, 32), 256, 0, stream>>>(h, h_bf, hT_bf);
    init_c<<<4096, 256, 0, stream>>>(out_c, bias_red);

    // 3) ms = s @ Wphi^T + bias -> bf16 (8192 x 2048, K=512), grid 16x64
    gemm_mfma<<<16 * 64, 256, 0, stream>>>(
        s_bf, Wphi_b, nullptr, ms_bf, bias_phi, 0,
        512, 512, 512, 2048, 0, 0, 0, 0, 0, 0, 1, /*nxs*/4, /*zbits*/0);

    // 4) mh = h @ Wpsi^T + bias -> bf16 (32768 x 512, K=512), grid 4x256
    gemm_mfma<<<4 * 256, 256, 0, stream>>>(
        h_bf, Wpsi_b, nullptr, mh_bf, bias_psi, 0,
        512, 512, 512, 512, 0, 0, 0, 0, 0, 0, 1, /*nxs*/2, /*zbits*/0);

    // 5..7) per batch-chunk: fused scores+softmax, ctx GEMM, reduce GEMM
    for (int q = 0; q < S; q++) {
        // fused e+softmax: writes out_a (f32, global layout) + aReg (bf16)
        fused_esm<<<16 * nb, 512, 0, stream>>>(
            ms_bf + (long)q * nb * 256 * 2048,
            mh_bf + (long)q * nb * 1024 * 512,
            out_a + (long)q * nb * 256 * 1024,
            aReg, lognb);

        // ctx = a . h (via hT, NT): per (h,bbl) 256x512, K=1024
        gemm_mfma<<<8 * 4 * nb, 256, 0, stream>>>(
            aReg, hT_bf + (long)q * nb * 512 * 1024, nullptr, ctxReg, nullptr, 0,
            1024, 1024, 1024, 2048,
            /*sAh*/ (long)nb * 256 * 1024, /*sAb*/ (long)256 * 1024,
            /*sBh*/ 0, /*sBb*/ (long)512 * 1024,
            /*sCh*/ 512, /*sCb*/ (long)256 * 2048,
            nb, /*nxs*/2, /*zbits*/lognb + 2);

        // c += ctx @ Wred^T (split-K x4, atomic f32; bias pre-initialized)
        gemm_mfma<<<(2 * nb) * 4 * 4, 256, 0, stream>>>(
            ctxReg, Wred_b, out_c + (long)q * nb * 256 * 512, nullptr, nullptr, 1,
            512, 2048, 2048, 512,
            /*sAh*/ 512, /*sAb*/ 0,
            /*sBh*/ 512, /*sBb*/ 0,
            /*sCh*/ 0, /*sCb*/ 0,
            1, /*nxs*/2, /*zbits*/2);
    }
}